// Round 1
// baseline (3682.223 us; speedup 1.0000x reference)
//
#include <hip/hip_runtime.h>
#include <float.h>
#include <math.h>

#define M_ROWS 32768
#define K_CODES 8192
#define DDIM 256

// ---------------- kernel 1: normalize E rows -> En (fp32) ----------------
__global__ __launch_bounds__(256) void k_norm_E(const float* __restrict__ E,
                                                float* __restrict__ En) {
    int wid  = threadIdx.x >> 6;   // wave in block 0..3
    int lane = threadIdx.x & 63;
    int row  = blockIdx.x * 4 + wid;
    const float* e = E + (size_t)row * DDIM;
    float v[4];
    float ssq = 0.f;
#pragma unroll
    for (int p = 0; p < 4; ++p) { v[p] = e[lane + 64 * p]; ssq += v[p] * v[p]; }
#pragma unroll
    for (int off = 32; off >= 1; off >>= 1) ssq += __shfl_xor(ssq, off);
    float inv = 1.f / fmaxf(sqrtf(ssq), 1e-8f);
    float* o = En + (size_t)row * DDIM;
#pragma unroll
    for (int p = 0; p < 4; ++p) o[lane + 64 * p] = v[p] * inv;
}

// ---------------- kernel 2: fused sims + row-argmax ----------------
// sims[m,k] = dot(z[m], En[k])  (z unnormalized: positive row-scale is
// argmax-invariant over k).  BM=64 rows/block, loop all K in BN=128 tiles.
#define BM 64
#define BN 128
#define DC 32   // D-chunk staged in LDS (floats)

__global__ __launch_bounds__(256, 1) void k_argmax(const float* __restrict__ z,
                                                   const float* __restrict__ En,
                                                   int* __restrict__ bestIdx) {
    __shared__ float As[BM * DC];   // [64][32], XOR-swizzled float4 granules
    __shared__ float Bs[BN * DC];   // [128][32], XOR-swizzled

    float4* As4 = (float4*)As;
    float4* Bs4 = (float4*)Bs;

    const int tid = threadIdx.x;
    const int tx  = tid & 15;       // col-group 0..15 (owns 8 cols)
    const int ty  = tid >> 4;       // row-group 0..15 (owns 4 rows)
    const int m0  = blockIdx.x * BM;

    // staging assignments
    const int ra = tid >> 2;            // A: rows 0..63, 2 float4 each
    const int ga0 = (tid & 3) * 2;      // granules ga0, ga0+1
    const int swa = (ra >> 3) & 7;
    const int rb = tid >> 1;            // B: rows 0..127, 4 float4 each
    const int gb0 = (tid & 1) * 4;      // granules gb0..gb0+3
    const int swb = (rb >> 3) & 7;

    float best[4];
    int   bidx[4];
#pragma unroll
    for (int i = 0; i < 4; ++i) { best[i] = -FLT_MAX; bidx[i] = 0; }

    for (int kt = 0; kt < K_CODES; kt += BN) {
        float acc[4][8];
#pragma unroll
        for (int i = 0; i < 4; ++i)
#pragma unroll
            for (int j = 0; j < 8; ++j) acc[i][j] = 0.f;

        for (int dc0 = 0; dc0 < DDIM; dc0 += DC) {
            // ---- stage A (64x32) and B (128x32) into swizzled LDS ----
            const float* gA = z  + (size_t)(m0 + ra) * DDIM + dc0 + ga0 * 4;
            const float* gB = En + (size_t)(kt + rb) * DDIM + dc0 + gb0 * 4;
#pragma unroll
            for (int u = 0; u < 2; ++u)
                As4[ra * 8 + ((ga0 + u) ^ swa)] = *(const float4*)(gA + 4 * u);
#pragma unroll
            for (int u = 0; u < 4; ++u)
                Bs4[rb * 8 + ((gb0 + u) ^ swb)] = *(const float4*)(gB + 4 * u);
            __syncthreads();

            // ---- compute: 8 d4-steps of 4 d each ----
#pragma unroll
            for (int d4 = 0; d4 < 8; ++d4) {
                float4 a[4], b[8];
#pragma unroll
                for (int i = 0; i < 4; ++i) {
                    int r = ty * 4 + i;
                    a[i] = As4[r * 8 + (d4 ^ ((r >> 3) & 7))];
                }
#pragma unroll
                for (int j = 0; j < 8; ++j) {
                    int r = tx * 8 + j;
                    b[j] = Bs4[r * 8 + (d4 ^ ((r >> 3) & 7))];
                }
#pragma unroll
                for (int i = 0; i < 4; ++i)
#pragma unroll
                    for (int j = 0; j < 8; ++j)
                        acc[i][j] += a[i].x * b[j].x + a[i].y * b[j].y +
                                     a[i].z * b[j].z + a[i].w * b[j].w;
            }
            __syncthreads();
        }

        // ---- fold this k-tile into running best (ascending k per thread) ----
#pragma unroll
        for (int i = 0; i < 4; ++i)
#pragma unroll
            for (int j = 0; j < 8; ++j) {
                float v = acc[i][j];
                if (v > best[i]) { best[i] = v; bidx[i] = kt + tx * 8 + j; }
            }
    }

    // ---- reduce across the 16 col-group lanes sharing each row ----
#pragma unroll
    for (int i = 0; i < 4; ++i) {
        float v  = best[i];
        int   ix = bidx[i];
#pragma unroll
        for (int off = 1; off < 16; off <<= 1) {
            float ov = __shfl_xor(v, off);
            int   oi = __shfl_xor(ix, off);
            if (ov > v || (ov == v && oi < ix)) { v = ov; ix = oi; }
        }
        if (tx == 0) bestIdx[m0 + ty * 4 + i] = ix;
    }
}

// ---------------- kernel 3: gather / zq_st / per-row loss / idx ----------------
__global__ __launch_bounds__(256) void k_final(const float* __restrict__ z,
                                               const float* __restrict__ E,
                                               const int* __restrict__ bestIdx,
                                               float* __restrict__ out,
                                               float* __restrict__ rowloss) {
    int wid  = threadIdx.x >> 6;
    int lane = threadIdx.x & 63;
    int m    = blockIdx.x * 4 + wid;
    int idx  = bestIdx[m];

    const float* zr = z + (size_t)m * DDIM;
    const float* er = E + (size_t)idx * DDIM;

    float zv[4], ev[4];
    float sz = 0.f, se = 0.f;
#pragma unroll
    for (int p = 0; p < 4; ++p) {
        zv[p] = zr[lane + 64 * p]; sz += zv[p] * zv[p];
        ev[p] = er[lane + 64 * p]; se += ev[p] * ev[p];
    }
#pragma unroll
    for (int off = 32; off >= 1; off >>= 1) {
        sz += __shfl_xor(sz, off);
        se += __shfl_xor(se, off);
    }
    float nz = fmaxf(sqrtf(sz), 1e-8f);
    float ne = fmaxf(sqrtf(se), 1e-8f);

    float rs = 0.f;
    float* zq = out + 1 + (size_t)m * DDIM;
#pragma unroll
    for (int p = 0; p < 4; ++p) {
        float zn = zv[p] / nz;
        float en = ev[p] / ne;
        float d  = en - zn;
        rs += d * d;
        // straight-through: z + (zq - z), matching ref arithmetic exactly
        zq[lane + 64 * p] = zv[p] + (ev[p] - zv[p]);
    }
#pragma unroll
    for (int off = 32; off >= 1; off >>= 1) rs += __shfl_xor(rs, off);

    if (lane == 0) {
        rowloss[m] = rs;
        out[1 + (size_t)M_ROWS * DDIM + m] = (float)idx;  // idx as float
    }
}

// ---------------- kernel 4: deterministic loss reduction ----------------
__global__ __launch_bounds__(256) void k_loss(const float* __restrict__ rowloss,
                                              float* __restrict__ out) {
    __shared__ double sm[256];
    double s = 0.0;
    for (int i = threadIdx.x; i < M_ROWS; i += 256) s += (double)rowloss[i];
    sm[threadIdx.x] = s;
    __syncthreads();
    for (int st = 128; st > 0; st >>= 1) {
        if (threadIdx.x < st) sm[threadIdx.x] += sm[threadIdx.x + st];
        __syncthreads();
    }
    if (threadIdx.x == 0) {
        float c = (float)(sm[0] / (double)((size_t)M_ROWS * DDIM));
        out[0] = c + 0.05f * c;   // commit + BETA*codebook (numerically equal)
    }
}

extern "C" void kernel_launch(void* const* d_in, const int* in_sizes, int n_in,
                              void* d_out, int out_size, void* d_ws, size_t ws_size,
                              hipStream_t stream) {
    const float* z = (const float*)d_in[0];
    const float* E = (const float*)d_in[1];
    float* out = (float*)d_out;

    char* ws = (char*)d_ws;
    float* En      = (float*)ws;                                      // 8 MB
    int*   bestIdx = (int*)(ws + (size_t)K_CODES * DDIM * 4);         // 128 KB
    float* rowloss = (float*)(ws + (size_t)K_CODES * DDIM * 4
                                 + (size_t)M_ROWS * 4);               // 128 KB

    k_norm_E<<<K_CODES / 4, 256, 0, stream>>>(E, En);
    k_argmax<<<M_ROWS / BM, 256, 0, stream>>>(z, En, bestIdx);
    k_final<<<M_ROWS / 4, 256, 0, stream>>>(z, E, bestIdx, out, rowloss);
    k_loss<<<1, 256, 0, stream>>>(rowloss, out);
}